// Round 3
// baseline (537.608 us; speedup 1.0000x reference)
//
#include <hip/hip_runtime.h>
#include <hip/hip_bf16.h>

#define H 128

using bf16x8 = __attribute__((ext_vector_type(8))) short;
using f32x4  = __attribute__((ext_vector_type(4))) float;

__device__ inline unsigned short f2bf(float f) {
    unsigned u = __float_as_uint(f);
    unsigned r = (u + 0x7fffu + ((u >> 16) & 1u)) >> 16;
    return (unsigned short)r;
}
__device__ inline float bf2f(unsigned short b) {
    return __uint_as_float(((unsigned)b) << 16);
}

// ---------------- CSR build ----------------

__global__ void k_zero_i32(int* __restrict__ p, int n) {
    int i = blockIdx.x * blockDim.x + threadIdx.x;
    if (i < n) p[i] = 0;
}

__global__ void k_count(const int* __restrict__ dst, int* __restrict__ deg, int e) {
    int i = blockIdx.x * blockDim.x + threadIdx.x;
    if (i < e) atomicAdd(&deg[dst[i]], 1);
}

__global__ __launch_bounds__(1024) void k_scan_partial(const int* __restrict__ deg,
                                                       int* __restrict__ partials, int n) {
    __shared__ int sm[1024];
    int t = threadIdx.x;
    int i = blockIdx.x * 1024 + t;
    sm[t] = (i < n) ? deg[i] : 0;
    __syncthreads();
    for (int s = 512; s > 0; s >>= 1) {
        if (t < s) sm[t] += sm[t + s];
        __syncthreads();
    }
    if (t == 0) partials[blockIdx.x] = sm[0];
}

__global__ __launch_bounds__(64) void k_scan_base(int* __restrict__ partials, int nb,
                                                  int* __restrict__ offsets, int n) {
    __shared__ int sm[64];
    int t = threadIdx.x;
    int v = (t < nb) ? partials[t] : 0;
    sm[t] = v;
    __syncthreads();
    for (int off = 1; off < 64; off <<= 1) {
        int x = 0;
        if (t >= off) x = sm[t - off];
        __syncthreads();
        if (t >= off) sm[t] += x;
        __syncthreads();
    }
    if (t < nb) partials[t] = sm[t] - v;
    if (t == 63) offsets[n] = sm[63];
}

__global__ __launch_bounds__(1024) void k_scan_final(const int* __restrict__ deg,
                                                     const int* __restrict__ partials,
                                                     int* __restrict__ offsets,
                                                     int* __restrict__ cursor,
                                                     float* __restrict__ inv_deg, int n) {
    __shared__ int sm[1024];
    int t = threadIdx.x;
    int b = blockIdx.x;
    int i = b * 1024 + t;
    int v = (i < n) ? deg[i] : 0;
    sm[t] = v;
    __syncthreads();
    for (int off = 1; off < 1024; off <<= 1) {
        int x = 0;
        if (t >= off) x = sm[t - off];
        __syncthreads();
        if (t >= off) sm[t] += x;
        __syncthreads();
    }
    if (i < n) {
        int excl = partials[b] + sm[t] - v;
        offsets[i] = excl;
        cursor[i]  = excl;
        inv_deg[i] = 1.0f / fmaxf((float)v, 1.0f);
    }
}

__global__ void k_fill(const int* __restrict__ src, const int* __restrict__ dst,
                       int* __restrict__ cursor, int* __restrict__ csr, int e) {
    int i = blockIdx.x * blockDim.x + threadIdx.x;
    if (i < e) {
        int d = dst[i];
        int pos = atomicAdd(&cursor[d], 1);
        csr[pos] = src[i];
    }
}

// W2[l][j][k] (j=0..127, k=0..255): k<128 -> Wl[l][j][k], else Wr[l][j][k-128].
// Split into bf16 hi/lo.
__global__ void k_wsplit(const float* __restrict__ Wl, const float* __restrict__ Wr,
                         unsigned short* __restrict__ w_hi, unsigned short* __restrict__ w_lo,
                         int total) {
    int idx = blockIdx.x * blockDim.x + threadIdx.x;
    if (idx >= total) return;
    int l = idx / (H * 256);
    int rem = idx - l * H * 256;
    int j = rem >> 8;
    int k = rem & 255;
    float v;
    if (k < H) v = Wl[(size_t)l * H * H + j * H + k];
    else       v = Wr[(size_t)l * H * H + j * H + (k - H)];
    unsigned short hi = f2bf(v);
    unsigned short lo = f2bf(v - bf2f(hi));
    w_hi[idx] = hi;
    w_lo[idx] = lo;
}

// ---------------- per-layer kernels ----------------

// mean aggregation (fp32 gather) + split agg -> bf16 hi/lo + split own h row -> hi/lo.
// 32 lanes per node (float4 each), 8 nodes per 256-thread block.
__global__ __launch_bounds__(256) void k_agg(const float* __restrict__ h,
                                             const int* __restrict__ csr,
                                             const int* __restrict__ offsets,
                                             const float* __restrict__ inv_deg,
                                             unsigned short* __restrict__ agg_hi,
                                             unsigned short* __restrict__ agg_lo,
                                             unsigned short* __restrict__ h_hi,
                                             unsigned short* __restrict__ h_lo, int n) {
    int node = blockIdx.x * 8 + (threadIdx.x >> 5);
    int lane = threadIdx.x & 31;
    if (node >= n) return;
    int s = offsets[node];
    int eend = offsets[node + 1];
    const float4* hv = (const float4*)h;
    float4 acc = make_float4(0.f, 0.f, 0.f, 0.f);
    if (s < eend) {
        int src = csr[s];
        float4 v = hv[(size_t)src * 32 + lane];
        for (int p = s + 1; p < eend; ++p) {
            int nsrc = csr[p];
            float4 nv = hv[(size_t)nsrc * 32 + lane];
            acc.x += v.x; acc.y += v.y; acc.z += v.z; acc.w += v.w;
            v = nv;
        }
        acc.x += v.x; acc.y += v.y; acc.z += v.z; acc.w += v.w;
    }
    float w = inv_deg[node];
    acc.x *= w; acc.y *= w; acc.z *= w; acc.w *= w;

    // split agg
    ushort4 ahi, alo;
    ahi.x = f2bf(acc.x); alo.x = f2bf(acc.x - bf2f(ahi.x));
    ahi.y = f2bf(acc.y); alo.y = f2bf(acc.y - bf2f(ahi.y));
    ahi.z = f2bf(acc.z); alo.z = f2bf(acc.z - bf2f(ahi.z));
    ahi.w = f2bf(acc.w); alo.w = f2bf(acc.w - bf2f(ahi.w));
    ((ushort4*)agg_hi)[(size_t)node * 32 + lane] = ahi;
    ((ushort4*)agg_lo)[(size_t)node * 32 + lane] = alo;

    // split own h row (hv row read is L2-hot from the gathers)
    float4 hrow = hv[(size_t)node * 32 + lane];
    ushort4 hhi, hlo;
    hhi.x = f2bf(hrow.x); hlo.x = f2bf(hrow.x - bf2f(hhi.x));
    hhi.y = f2bf(hrow.y); hlo.y = f2bf(hrow.y - bf2f(hhi.y));
    hhi.z = f2bf(hrow.z); hlo.z = f2bf(hrow.z - bf2f(hhi.z));
    hhi.w = f2bf(hrow.w); hlo.w = f2bf(hrow.w - bf2f(hhi.w));
    ((ushort4*)h_hi)[(size_t)node * 32 + lane] = hhi;
    ((ushort4*)h_lo)[(size_t)node * 32 + lane] = hlo;
}

// out[N][128] = [agg|h][N][256] @ Wcat[256][128] + bias (split-bf16 MFMA), optional relu.
// Block = 256 threads = 4 waves; block tile 64 rows; wave tile 16 rows x 128 cols.
// No LDS: direct global->register fragments (W2 is 128KB, L2-hot).
__global__ __launch_bounds__(256) void k_gemm_mfma(const unsigned short* __restrict__ agg_hi,
                                                   const unsigned short* __restrict__ agg_lo,
                                                   const unsigned short* __restrict__ h_hi,
                                                   const unsigned short* __restrict__ h_lo,
                                                   const unsigned short* __restrict__ w_hi,
                                                   const unsigned short* __restrict__ w_lo,
                                                   const float* __restrict__ bias,
                                                   float* __restrict__ out, int n, int relu) {
    int wv = threadIdx.x >> 6;
    int lane = threadIdx.x & 63;
    int r16 = lane & 15;     // A row within tile / B col within tile / C col
    int kq = lane >> 4;      // 0..3 quarter-wave -> k-subgroup
    int rowbase = blockIdx.x * 64 + wv * 16;
    int arow = rowbase + r16;
    bool rowok = arow < n;

    f32x4 acc[8];
#pragma unroll
    for (int c = 0; c < 8; ++c) acc[c] = (f32x4){0.f, 0.f, 0.f, 0.f};

#pragma unroll
    for (int s = 0; s < 8; ++s) {
        const unsigned short* Ah = (s < 4) ? agg_hi : h_hi;
        const unsigned short* Al = (s < 4) ? agg_lo : h_lo;
        int ka = (s & 3) * 32 + kq * 8;     // k within the 128-wide A source
        bf16x8 a_hi = {}, a_lo = {};
        if (rowok) {
            a_hi = *(const bf16x8*)(Ah + (size_t)arow * H + ka);
            a_lo = *(const bf16x8*)(Al + (size_t)arow * H + ka);
        }
        int kw = s * 32 + kq * 8;           // k within the 256-wide W2 row
#pragma unroll
        for (int c = 0; c < 8; ++c) {
            int j = c * 16 + r16;
            bf16x8 b_hi = *(const bf16x8*)(w_hi + (size_t)j * 256 + kw);
            bf16x8 b_lo = *(const bf16x8*)(w_lo + (size_t)j * 256 + kw);
            acc[c] = __builtin_amdgcn_mfma_f32_16x16x32_bf16(a_hi, b_hi, acc[c], 0, 0, 0);
            acc[c] = __builtin_amdgcn_mfma_f32_16x16x32_bf16(a_hi, b_lo, acc[c], 0, 0, 0);
            acc[c] = __builtin_amdgcn_mfma_f32_16x16x32_bf16(a_lo, b_hi, acc[c], 0, 0, 0);
        }
    }

#pragma unroll
    for (int c = 0; c < 8; ++c) {
        int col = c * 16 + r16;
        float b = bias[col];
#pragma unroll
        for (int r = 0; r < 4; ++r) {
            int grow = rowbase + kq * 4 + r;
            if (grow < n) {
                float v = acc[c][r] + b;
                if (relu) v = fmaxf(v, 0.f);
                out[(size_t)grow * H + col] = v;
            }
        }
    }
}

// ---------------- launch ----------------

extern "C" void kernel_launch(void* const* d_in, const int* in_sizes, int n_in,
                              void* d_out, int out_size, void* d_ws, size_t ws_size,
                              hipStream_t stream) {
    const float* x  = (const float*)d_in[0];
    const int*   ei = (const int*)d_in[1];
    const float* Wl = (const float*)d_in[2];
    const float* bl = (const float*)d_in[3];
    const float* Wr = (const float*)d_in[4];
    float* out = (float*)d_out;

    int n = in_sizes[0] / H;
    int e = in_sizes[1] / 2;
    const int* srcp = ei;
    const int* dstp = ei + e;

    char* w = (char*)d_ws;
    auto alloc = [&](size_t bytes) {
        char* p = w;
        w += (bytes + 255) & ~(size_t)255;
        return p;
    };
    int nb = (n + 1023) / 1024;
    int*            csr      = (int*)alloc((size_t)e * 4);
    int*            offsets  = (int*)alloc((size_t)(n + 1) * 4);
    int*            cursor   = (int*)alloc((size_t)n * 4);
    int*            deg      = (int*)alloc((size_t)n * 4);
    float*          inv_deg  = (float*)alloc((size_t)n * 4);
    int*            partials = (int*)alloc(64 * 4);
    unsigned short* w2_hi    = (unsigned short*)alloc((size_t)3 * H * 256 * 2);
    unsigned short* w2_lo    = (unsigned short*)alloc((size_t)3 * H * 256 * 2);
    unsigned short* agg_hi   = (unsigned short*)alloc((size_t)n * H * 2);
    unsigned short* agg_lo   = (unsigned short*)alloc((size_t)n * H * 2);
    unsigned short* h_hi     = (unsigned short*)alloc((size_t)n * H * 2);
    unsigned short* h_lo     = (unsigned short*)alloc((size_t)n * H * 2);
    float*          hbuf     = (float*)alloc((size_t)n * H * 4);

    // CSR + inv_deg + W split (once per launch)
    k_zero_i32<<<(n + 255) / 256, 256, 0, stream>>>(deg, n);
    k_count<<<(e + 255) / 256, 256, 0, stream>>>(dstp, deg, e);
    k_scan_partial<<<nb, 1024, 0, stream>>>(deg, partials, n);
    k_scan_base<<<1, 64, 0, stream>>>(partials, nb, offsets, n);
    k_scan_final<<<nb, 1024, 0, stream>>>(deg, partials, offsets, cursor, inv_deg, n);
    k_fill<<<(e + 255) / 256, 256, 0, stream>>>(srcp, dstp, cursor, csr, e);
    int wtot = 3 * H * 256;
    k_wsplit<<<(wtot + 255) / 256, 256, 0, stream>>>(Wl, Wr, w2_hi, w2_lo, wtot);

    const float* hin[3]  = {x, out, hbuf};
    float*       hout[3] = {out, hbuf, out};
    for (int l = 0; l < 3; ++l) {
        k_agg<<<(n + 7) / 8, 256, 0, stream>>>(hin[l], csr, offsets, inv_deg,
                                               agg_hi, agg_lo, h_hi, h_lo, n);
        k_gemm_mfma<<<(n + 63) / 64, 256, 0, stream>>>(agg_hi, agg_lo, h_hi, h_lo,
                                                       w2_hi + (size_t)l * H * 256,
                                                       w2_lo + (size_t)l * H * 256,
                                                       bl + (size_t)l * H, hout[l], n,
                                                       l < 2 ? 1 : 0);
    }
}

// Round 9
// 400.425 us; speedup vs baseline: 1.3426x; 1.3426x over previous
//
#include <hip/hip_runtime.h>
#include <hip/hip_bf16.h>

#define H 128

using bf16x8 = __attribute__((ext_vector_type(8))) short;
using f32x4  = __attribute__((ext_vector_type(4))) float;

__device__ inline unsigned short f2bf(float f) {
    unsigned u = __float_as_uint(f);
    unsigned r = (u + 0x7fffu + ((u >> 16) & 1u)) >> 16;
    return (unsigned short)r;
}
__device__ inline float bf2f(unsigned short b) {
    return __uint_as_float(((unsigned)b) << 16);
}

// ---------------- CSR build ----------------

__global__ void k_zero_i32(int* __restrict__ p, int n) {
    int i = blockIdx.x * blockDim.x + threadIdx.x;
    if (i < n) p[i] = 0;
}

__global__ void k_count(const int* __restrict__ dst, int* __restrict__ deg, int e) {
    int i = blockIdx.x * blockDim.x + threadIdx.x;
    if (i < e) atomicAdd(&deg[dst[i]], 1);
}

__global__ __launch_bounds__(1024) void k_scan_partial(const int* __restrict__ deg,
                                                       int* __restrict__ partials, int n) {
    __shared__ int sm[1024];
    int t = threadIdx.x;
    int i = blockIdx.x * 1024 + t;
    sm[t] = (i < n) ? deg[i] : 0;
    __syncthreads();
    for (int s = 512; s > 0; s >>= 1) {
        if (t < s) sm[t] += sm[t + s];
        __syncthreads();
    }
    if (t == 0) partials[blockIdx.x] = sm[0];
}

__global__ __launch_bounds__(64) void k_scan_base(int* __restrict__ partials, int nb,
                                                  int* __restrict__ offsets, int n) {
    __shared__ int sm[64];
    int t = threadIdx.x;
    int v = (t < nb) ? partials[t] : 0;
    sm[t] = v;
    __syncthreads();
    for (int off = 1; off < 64; off <<= 1) {
        int x = 0;
        if (t >= off) x = sm[t - off];
        __syncthreads();
        if (t >= off) sm[t] += x;
        __syncthreads();
    }
    if (t < nb) partials[t] = sm[t] - v;
    if (t == 63) offsets[n] = sm[63];
}

__global__ __launch_bounds__(1024) void k_scan_final(const int* __restrict__ deg,
                                                     const int* __restrict__ partials,
                                                     int* __restrict__ offsets,
                                                     int* __restrict__ cursor,
                                                     float* __restrict__ inv_deg, int n) {
    __shared__ int sm[1024];
    int t = threadIdx.x;
    int b = blockIdx.x;
    int i = b * 1024 + t;
    int v = (i < n) ? deg[i] : 0;
    sm[t] = v;
    __syncthreads();
    for (int off = 1; off < 1024; off <<= 1) {
        int x = 0;
        if (t >= off) x = sm[t - off];
        __syncthreads();
        if (t >= off) sm[t] += x;
        __syncthreads();
    }
    if (i < n) {
        int excl = partials[b] + sm[t] - v;
        offsets[i] = excl;
        cursor[i]  = excl;
        inv_deg[i] = 1.0f / fmaxf((float)v, 1.0f);
    }
}

__global__ void k_fill(const int* __restrict__ src, const int* __restrict__ dst,
                       int* __restrict__ cursor, int* __restrict__ csr, int e) {
    int i = blockIdx.x * blockDim.x + threadIdx.x;
    if (i < e) {
        int d = dst[i];
        int pos = atomicAdd(&cursor[d], 1);
        csr[pos] = src[i];
    }
}

// W fragment-major: Wf[l][s][c][hl][lane][8] bf16 (hl: 0=hi 1=lo).
// Fragment for (s,c): col j = c*16 + (lane&15), k = s*32 + (lane>>4)*8 + jj.
// k<128 -> Wl[l][j][k] ; k>=128 -> Wr[l][j][k-128].
// FIX(r8): writer now emits hi-block [64][8] then lo-block [64][8] per (l,s,c),
// matching the reader (previous version interleaved hi/lo per lane -> absmax 1.2).
__global__ void k_wsplit(const float* __restrict__ Wl, const float* __restrict__ Wr,
                         unsigned short* __restrict__ Wf, int total) {
    int idx = blockIdx.x * blockDim.x + threadIdx.x;   // (l, s, c, lane)
    if (idx >= total) return;
    int l = idx >> 12;
    int rem = idx & 4095;
    int s = rem >> 9;
    int c = (rem >> 6) & 7;
    int lane = rem & 63;
    int j = c * 16 + (lane & 15);
    int k0 = s * 32 + (lane >> 4) * 8;
    size_t fc = (size_t)(idx >> 6);              // fragment index (l*8+s)*8+c
    size_t hbase = (fc * 2 * 64 + lane) * 8;     // [fc][hl=0][lane][8]
    size_t lbase = hbase + 512;                  // [fc][hl=1][lane][8]
    for (int jj = 0; jj < 8; ++jj) {
        int k = k0 + jj;
        float v;
        if (k < H) v = Wl[(size_t)l * H * H + j * H + k];
        else       v = Wr[(size_t)l * H * H + j * H + (k - H)];
        unsigned short hi = f2bf(v);
        unsigned short lo = f2bf(v - bf2f(hi));
        Wf[hbase + jj] = hi;
        Wf[lbase + jj] = lo;
    }
}

// ---------------- per-layer kernels ----------------

// mean aggregation (fp32 gather, 2-wide ILP) + write A hi/lo in MFMA-fragment-major:
// A[tile][s][lane][8], s=0..3 from agg, s=4..7 from own h row.
// 32 lanes per node (4 k-values each), 8 nodes per 256-thread block.
__global__ __launch_bounds__(256) void k_agg(const float* __restrict__ h,
                                             const int* __restrict__ csr,
                                             const int* __restrict__ offsets,
                                             const float* __restrict__ inv_deg,
                                             unsigned short* __restrict__ A_hi,
                                             unsigned short* __restrict__ A_lo, int n) {
    int node = blockIdx.x * 8 + (threadIdx.x >> 5);
    int l4 = threadIdx.x & 31;
    if (node >= n) return;
    int s = offsets[node];
    int eend = offsets[node + 1];
    const float4* hv = (const float4*)h;
    float4 a0 = make_float4(0.f, 0.f, 0.f, 0.f);
    float4 a1 = make_float4(0.f, 0.f, 0.f, 0.f);
    int p = s;
    for (; p + 1 < eend; p += 2) {
        int i0 = csr[p], i1 = csr[p + 1];
        float4 v0 = hv[(size_t)i0 * 32 + l4];
        float4 v1 = hv[(size_t)i1 * 32 + l4];
        a0.x += v0.x; a0.y += v0.y; a0.z += v0.z; a0.w += v0.w;
        a1.x += v1.x; a1.y += v1.y; a1.z += v1.z; a1.w += v1.w;
    }
    if (p < eend) {
        int i0 = csr[p];
        float4 v0 = hv[(size_t)i0 * 32 + l4];
        a0.x += v0.x; a0.y += v0.y; a0.z += v0.z; a0.w += v0.w;
    }
    float w = inv_deg[node];
    float4 acc;
    acc.x = (a0.x + a1.x) * w; acc.y = (a0.y + a1.y) * w;
    acc.z = (a0.z + a1.z) * w; acc.w = (a0.w + a1.w) * w;

    // fragment-major address for this lane's 4 k-values (k = l4*4 ..+3)
    int tile = node >> 4;
    size_t base = ((size_t)(tile * 8 + (l4 >> 3)) * 64 + ((l4 >> 1) & 3) * 16 + (node & 15)) * 8
                  + (l4 & 1) * 4;

    ushort4 ahi, alo;
    ahi.x = f2bf(acc.x); alo.x = f2bf(acc.x - bf2f(ahi.x));
    ahi.y = f2bf(acc.y); alo.y = f2bf(acc.y - bf2f(ahi.y));
    ahi.z = f2bf(acc.z); alo.z = f2bf(acc.z - bf2f(ahi.z));
    ahi.w = f2bf(acc.w); alo.w = f2bf(acc.w - bf2f(ahi.w));
    *(ushort4*)(A_hi + base) = ahi;
    *(ushort4*)(A_lo + base) = alo;

    // own h row -> s+4 slot (offset = 4 fragments * 512 ushorts)
    float4 hrow = hv[(size_t)node * 32 + l4];
    ushort4 hhi, hlo;
    hhi.x = f2bf(hrow.x); hlo.x = f2bf(hrow.x - bf2f(hhi.x));
    hhi.y = f2bf(hrow.y); hlo.y = f2bf(hrow.y - bf2f(hhi.y));
    hhi.z = f2bf(hrow.z); hlo.z = f2bf(hrow.z - bf2f(hhi.z));
    hhi.w = f2bf(hrow.w); hlo.w = f2bf(hrow.w - bf2f(hhi.w));
    *(ushort4*)(A_hi + base + 2048) = hhi;
    *(ushort4*)(A_lo + base + 2048) = hlo;
}

// out[N][128] = [agg|h][N][256] @ W^T + bias (split-bf16 MFMA), optional relu.
// 256 threads = 4 waves; block covers 128 rows = 8 tiles; wave wv owns tiles
// blk*8+wv*2 and +1 (B fragments reused across the two tiles from registers).
// All loads are lane-contiguous (fragment-major) -> fully coalesced, no LDS.
__global__ __launch_bounds__(256) void k_gemm_mfma(const unsigned short* __restrict__ A_hi,
                                                   const unsigned short* __restrict__ A_lo,
                                                   const unsigned short* __restrict__ Wf,
                                                   const float* __restrict__ bias,
                                                   float* __restrict__ out, int n, int relu,
                                                   int ntiles) {
    int wv = threadIdx.x >> 6;
    int lane = threadIdx.x & 63;
    int r16 = lane & 15;
    int kq = lane >> 4;
    int t0 = blockIdx.x * 8 + wv * 2;
    int t1 = t0 + 1;
    bool ok0 = t0 < ntiles;
    bool ok1 = t1 < ntiles;

    f32x4 acc[2][8];
#pragma unroll
    for (int t = 0; t < 2; ++t)
#pragma unroll
        for (int c = 0; c < 8; ++c) acc[t][c] = (f32x4){0.f, 0.f, 0.f, 0.f};

#pragma unroll
    for (int s = 0; s < 8; ++s) {
        bf16x8 a0h = {}, a0l = {}, a1h = {}, a1l = {};
        if (ok0) {
            size_t ab = ((size_t)(t0 * 8 + s) * 64 + lane) * 8;
            a0h = *(const bf16x8*)(A_hi + ab);
            a0l = *(const bf16x8*)(A_lo + ab);
        }
        if (ok1) {
            size_t ab = ((size_t)(t1 * 8 + s) * 64 + lane) * 8;
            a1h = *(const bf16x8*)(A_hi + ab);
            a1l = *(const bf16x8*)(A_lo + ab);
        }
#pragma unroll
        for (int c = 0; c < 8; ++c) {
            size_t wb = (((size_t)(s * 8 + c) * 2) * 64 + lane) * 8;
            bf16x8 b_hi = *(const bf16x8*)(Wf + wb);
            bf16x8 b_lo = *(const bf16x8*)(Wf + wb + 512);
            acc[0][c] = __builtin_amdgcn_mfma_f32_16x16x32_bf16(a0h, b_hi, acc[0][c], 0, 0, 0);
            acc[0][c] = __builtin_amdgcn_mfma_f32_16x16x32_bf16(a0h, b_lo, acc[0][c], 0, 0, 0);
            acc[0][c] = __builtin_amdgcn_mfma_f32_16x16x32_bf16(a0l, b_hi, acc[0][c], 0, 0, 0);
            acc[1][c] = __builtin_amdgcn_mfma_f32_16x16x32_bf16(a1h, b_hi, acc[1][c], 0, 0, 0);
            acc[1][c] = __builtin_amdgcn_mfma_f32_16x16x32_bf16(a1h, b_lo, acc[1][c], 0, 0, 0);
            acc[1][c] = __builtin_amdgcn_mfma_f32_16x16x32_bf16(a1l, b_hi, acc[1][c], 0, 0, 0);
        }
    }

#pragma unroll
    for (int t = 0; t < 2; ++t) {
        int tile = t ? t1 : t0;
        if (tile >= ntiles) continue;
#pragma unroll
        for (int c = 0; c < 8; ++c) {
            int col = c * 16 + r16;
            float b = bias[col];
#pragma unroll
            for (int r = 0; r < 4; ++r) {
                int grow = tile * 16 + kq * 4 + r;
                if (grow < n) {
                    float v = acc[t][c][r] + b;
                    if (relu) v = fmaxf(v, 0.f);
                    out[(size_t)grow * H + col] = v;
                }
            }
        }
    }
}

// ---------------- launch ----------------

extern "C" void kernel_launch(void* const* d_in, const int* in_sizes, int n_in,
                              void* d_out, int out_size, void* d_ws, size_t ws_size,
                              hipStream_t stream) {
    const float* x  = (const float*)d_in[0];
    const int*   ei = (const int*)d_in[1];
    const float* Wl = (const float*)d_in[2];
    const float* bl = (const float*)d_in[3];
    const float* Wr = (const float*)d_in[4];
    float* out = (float*)d_out;

    int n = in_sizes[0] / H;
    int e = in_sizes[1] / 2;
    const int* srcp = ei;
    const int* dstp = ei + e;
    int ntiles = (n + 15) >> 4;

    char* w = (char*)d_ws;
    auto alloc = [&](size_t bytes) {
        char* p = w;
        w += (bytes + 255) & ~(size_t)255;
        return p;
    };
    int nb = (n + 1023) / 1024;
    int*            csr      = (int*)alloc((size_t)e * 4);
    int*            offsets  = (int*)alloc((size_t)(n + 1) * 4);
    int*            cursor   = (int*)alloc((size_t)n * 4);
    int*            deg      = (int*)alloc((size_t)n * 4);
    float*          inv_deg  = (float*)alloc((size_t)n * 4);
    int*            partials = (int*)alloc(64 * 4);
    unsigned short* Wf       = (unsigned short*)alloc((size_t)3 * 8 * 8 * 2 * 64 * 8 * 2);
    unsigned short* A_hi     = (unsigned short*)alloc((size_t)ntiles * 8 * 64 * 8 * 2);
    unsigned short* A_lo     = (unsigned short*)alloc((size_t)ntiles * 8 * 64 * 8 * 2);
    float*          hbuf     = (float*)alloc((size_t)n * H * 4);

    // CSR + inv_deg + W fragment-split (once per launch)
    k_zero_i32<<<(n + 255) / 256, 256, 0, stream>>>(deg, n);
    k_count<<<(e + 255) / 256, 256, 0, stream>>>(dstp, deg, e);
    k_scan_partial<<<nb, 1024, 0, stream>>>(deg, partials, n);
    k_scan_base<<<1, 64, 0, stream>>>(partials, nb, offsets, n);
    k_scan_final<<<nb, 1024, 0, stream>>>(deg, partials, offsets, cursor, inv_deg, n);
    k_fill<<<(e + 255) / 256, 256, 0, stream>>>(srcp, dstp, cursor, csr, e);
    int wtot = 3 * 8 * 8 * 64;
    k_wsplit<<<(wtot + 255) / 256, 256, 0, stream>>>(Wl, Wr, Wf, wtot);

    const float* hin[3]  = {x, out, hbuf};
    float*       hout[3] = {out, hbuf, out};
    int gemm_grid = (ntiles + 7) / 8;
    for (int l = 0; l < 3; ++l) {
        k_agg<<<(n + 7) / 8, 256, 0, stream>>>(hin[l], csr, offsets, inv_deg, A_hi, A_lo, n);
        k_gemm_mfma<<<gemm_grid, 256, 0, stream>>>(A_hi, A_lo,
                                                   Wf + (size_t)l * 8 * 8 * 2 * 64 * 8,
                                                   bl + (size_t)l * H, hout[l], n,
                                                   l < 2 ? 1 : 0, ntiles);
    }
}